// Round 1
// baseline (258.013 us; speedup 1.0000x reference)
//
#include <hip/hip_runtime.h>
#include <cmath>

namespace {
constexpr int kN = 16, kC = 64, kT = 512, kV = 25, kS = 3, kR = 8, kO = 64;
constexpr int kTV = kT * kV;   // 12800
constexpr int kTT = 8;         // t-chunk per block in k3
constexpr int kUP = 28;        // padded V/u row length (16B-aligned float4 rows)
constexpr int kAOffFloats = kN * kC * kV;  // 25600 floats for xm, then a_pad
}  // namespace

// ---------------- kernel 1: xm[n,c,v] = mean_t x[n,c,t,v] ----------------
__global__ __launch_bounds__(256) void k1_mean(const float* __restrict__ x,
                                               float* __restrict__ xm) {
  const int bid = blockIdx.x;  // n*kC + c
  const float* base = x + (size_t)bid * kTV;
  float acc[kV];
#pragma unroll
  for (int v = 0; v < kV; ++v) acc[v] = 0.f;
  for (int t = threadIdx.x; t < kT; t += 256) {
    const float* row = base + t * kV;
#pragma unroll
    for (int v = 0; v < kV; ++v) acc[v] += row[v];
  }
#pragma unroll
  for (int v = 0; v < kV; ++v) {
    float a = acc[v];
#pragma unroll
    for (int off = 32; off >= 1; off >>= 1) a += __shfl_xor(a, off, 64);
    acc[v] = a;
  }
  __shared__ float red[4][kV];
  const int wave = threadIdx.x >> 6, lane = threadIdx.x & 63;
  if (lane == 0) {
#pragma unroll
    for (int v = 0; v < kV; ++v) red[wave][v] = acc[v];
  }
  __syncthreads();
  if (threadIdx.x < kV) {
    const float s = red[0][threadIdx.x] + red[1][threadIdx.x] +
                    red[2][threadIdx.x] + red[3][threadIdx.x];
    xm[bid * kV + threadIdx.x] = s * (1.0f / kT);
  }
}

// -------- kernel 2: a_pad[s,n,c,u,v(28)] = alpha*(W4.tanh(x1-x2)+b4)+A --------
__global__ __launch_bounds__(256) void k2_attn(
    const float* __restrict__ xm, const float* __restrict__ Ag,
    const float* __restrict__ alpha, const float* __restrict__ w1,
    const float* __restrict__ b1, const float* __restrict__ w2,
    const float* __restrict__ b2, const float* __restrict__ w4,
    const float* __restrict__ b4, const int* __restrict__ sparse,
    float* __restrict__ a_pad) {
  const float thr = (float)sparse[0];
  const int s = blockIdx.x >> 4;   // 0..2
  const int n = blockIdx.x & 15;   // 0..15
  __shared__ float xm_l[kC * kV];          // 1600
  __shared__ float x1_l[kR * kV];          // 200
  __shared__ float x2_l[kR * kV];          // 200
  __shared__ float att_l[kR * kV * kV];    // 5000
  __shared__ float w4_l[kO * kR];          // 512
  const int tid = threadIdx.x;
  for (int i = tid; i < kC * kV; i += 256) xm_l[i] = xm[n * (kC * kV) + i];
  for (int i = tid; i < kO * kR; i += 256) {
    const float w = w4[s * (kO * kR) + i];
    w4_l[i] = (fabsf(w) > thr) ? w : 0.f;
  }
  __syncthreads();
  // x1[r,u] = sum_c mask(w1)[r,c]*xm[c,u] + b1[r]; x2 same with w2/b2
  for (int i = tid; i < 2 * kR * kV; i += 256) {
    const int which = i / (kR * kV);
    const int idx = i % (kR * kV);
    const int r = idx / kV, u = idx % kV;
    const float* wrow = (which == 0 ? w1 : w2) + (s * kR + r) * kC;
    float acc = 0.f;
    for (int cc = 0; cc < kC; ++cc) {
      float w = wrow[cc];
      w = (fabsf(w) > thr) ? w : 0.f;
      acc += w * xm_l[cc * kV + u];
    }
    acc += (which == 0 ? b1 : b2)[s * kR + r];
    if (which == 0) x1_l[idx] = acc;
    else x2_l[idx] = acc;
  }
  __syncthreads();
  for (int i = tid; i < kR * kV * kV; i += 256) {
    const int r = i / (kV * kV), uv = i % (kV * kV);
    const int u = uv / kV, v = uv % kV;
    att_l[i] = tanhf(x1_l[r * kV + u] - x2_l[r * kV + v]);
  }
  __syncthreads();
  const float al = alpha[0];
  float* abase = a_pad + (size_t)(s * kN + n) * (kO * kV * kUP);
  for (int c = 0; c < kO; ++c) {
    const float b4v = b4[s * kO + c];
    for (int p = tid; p < kV * kUP; p += 256) {
      const int u = p / kUP, v = p % kUP;
      float val = 0.f;
      if (v < kV) {
        float acc = 0.f;
#pragma unroll
        for (int r = 0; r < kR; ++r)
          acc += w4_l[c * kR + r] * att_l[r * (kV * kV) + u * kV + v];
        val = al * (acc + b4v) + Ag[s * (kV * kV) + u * kV + v];
      }
      abase[c * (kV * kUP) + p] = val;  // v=25..27 zero-padded
    }
  }
}

// ------- kernel 3: fused x3 = mask(W3)x + b3 ; z += a.x3 ; relu(z + x) -------
__global__ __launch_bounds__(256, 2) void k3_main(
    const float* __restrict__ x, const float* __restrict__ w3,
    const float* __restrict__ b3, const float* __restrict__ a_pad,
    const int* __restrict__ sparse, float* __restrict__ y) {
  const float thr = (float)sparse[0];
  const int tb = blockIdx.x;  // t-chunk 0..63
  const int n = blockIdx.y;   // 0..15
  __shared__ __align__(16) float xs[kC * kTT * kUP];  // 14336 f = 57.3 KB
  __shared__ float w3_l[kC * 65];                     // 4160 f, +1 pad: no bank conflict
  const int tid = threadIdx.x;
  const float* xn = x + (size_t)n * kC * kTV;
  const float4* xg4 = reinterpret_cast<const float4*>(xn);
  // stage x[n, :, t0:t0+8, :] -> xs[c][t][u(28)] , coalesced float4
  for (int i4 = tid; i4 < kC * kTT * kV / 4; i4 += 256) {  // 3200
    const int cc = i4 / 50, r4 = i4 % 50;
    const float4 vv = xg4[cc * (kTV / 4) + tb * 50 + r4];
    const float vals[4] = {vv.x, vv.y, vv.z, vv.w};
    const int j = r4 * 4;
#pragma unroll
    for (int k = 0; k < 4; ++k) {
      const int t = (j + k) / kV, u = (j + k) % kV;
      xs[cc * (kTT * kUP) + t * kUP + u] = vals[k];
    }
  }
  // zero the u=25..27 pads so padded FMAs stay clean
  for (int i = tid; i < kC * kTT * (kUP - kV); i += 256) {
    const int cc = i / (kTT * 3), r = i % (kTT * 3);
    const int t = r / 3, u = kV + r % 3;
    xs[cc * (kTT * kUP) + t * kUP + u] = 0.f;
  }

  const int c = tid >> 2;   // output channel, 4 lanes share (coalesced a-reads)
  const int ts = tid & 3;   // t rows: ts and ts+4

  float acc0[kUP], acc1[kUP];
#pragma unroll
  for (int u = 0; u < kUP; ++u) {
    acc0[u] = 0.f;
    acc1[u] = 0.f;
  }

  for (int s = 0; s < kS; ++s) {
    __syncthreads();  // xs visible (s=0); w3_l from prev s fully consumed
    for (int i = tid; i < kC * kC; i += 256) {
      const float w = w3[s * kC * kC + i];
      w3_l[(i >> 6) * 65 + (i & 63)] = (fabsf(w) > thr) ? w : 0.f;
    }
    __syncthreads();
    // phase B: x3[t][u] = b3[c] + sum_c' mask(w3)[c][c'] * xs[c'][t][u]
    const float b3v = b3[s * kO + c];
    float x3a[kUP], x3b[kUP];
#pragma unroll
    for (int u = 0; u < kUP; ++u) {
      x3a[u] = (u < kV) ? b3v : 0.f;
      x3b[u] = (u < kV) ? b3v : 0.f;
    }
    for (int cp = 0; cp < kC; ++cp) {
      const float w = w3_l[c * 65 + cp];
      const float* xra = &xs[cp * (kTT * kUP) + ts * kUP];
      const float* xrb = xra + 4 * kUP;
#pragma unroll
      for (int q = 0; q < 7; ++q) {
        const float4 va = *reinterpret_cast<const float4*>(xra + q * 4);
        const float4 vb = *reinterpret_cast<const float4*>(xrb + q * 4);
        x3a[q * 4 + 0] += w * va.x;
        x3a[q * 4 + 1] += w * va.y;
        x3a[q * 4 + 2] += w * va.z;
        x3a[q * 4 + 3] += w * va.w;
        x3b[q * 4 + 0] += w * vb.x;
        x3b[q * 4 + 1] += w * vb.y;
        x3b[q * 4 + 2] += w * vb.z;
        x3b[q * 4 + 3] += w * vb.w;
      }
    }
    // phase Z: acc[v] += a[c][u][v] * x3[t][u]
    const float* ab = a_pad + ((size_t)((s * kN + n) * kO + c)) * (kV * kUP);
#pragma unroll
    for (int u = 0; u < kV; ++u) {
      const float xva = x3a[u], xvb = x3b[u];
#pragma unroll
      for (int q = 0; q < 7; ++q) {
        const float4 av = *reinterpret_cast<const float4*>(ab + u * kUP + q * 4);
        acc0[q * 4 + 0] += av.x * xva;
        acc1[q * 4 + 0] += av.x * xvb;
        acc0[q * 4 + 1] += av.y * xva;
        acc1[q * 4 + 1] += av.y * xvb;
        acc0[q * 4 + 2] += av.z * xva;
        acc1[q * 4 + 2] += av.z * xvb;
        acc0[q * 4 + 3] += av.w * xva;
        acc1[q * 4 + 3] += av.w * xvb;
      }
    }
  }
  __syncthreads();  // all xs reads done before overwrite
  {
    float* ra = &xs[c * (kTT * kUP) + ts * kUP];
    float* rb = ra + 4 * kUP;
#pragma unroll
    for (int v = 0; v < kV; ++v) {
      const float oa = fmaxf(acc0[v] + ra[v], 0.f);
      const float ob = fmaxf(acc1[v] + rb[v], 0.f);
      ra[v] = oa;
      rb[v] = ob;
    }
  }
  __syncthreads();
  float4* yg4 = reinterpret_cast<float4*>(y + (size_t)n * kC * kTV);
  for (int i4 = tid; i4 < kC * kTT * kV / 4; i4 += 256) {
    const int cc = i4 / 50, r4 = i4 % 50;
    const int j = r4 * 4;
    float4 vv;
    vv.x = xs[cc * (kTT * kUP) + ((j + 0) / kV) * kUP + (j + 0) % kV];
    vv.y = xs[cc * (kTT * kUP) + ((j + 1) / kV) * kUP + (j + 1) % kV];
    vv.z = xs[cc * (kTT * kUP) + ((j + 2) / kV) * kUP + (j + 2) % kV];
    vv.w = xs[cc * (kTT * kUP) + ((j + 3) / kV) * kUP + (j + 3) % kV];
    yg4[cc * (kTV / 4) + tb * 50 + r4] = vv;
  }
}

extern "C" void kernel_launch(void* const* d_in, const int* in_sizes, int n_in,
                              void* d_out, int out_size, void* d_ws, size_t ws_size,
                              hipStream_t stream) {
  const float* x = (const float*)d_in[0];
  const float* Ag = (const float*)d_in[1];
  const float* alpha = (const float*)d_in[2];
  const float* w1 = (const float*)d_in[3];
  const float* b1 = (const float*)d_in[4];
  const float* w2 = (const float*)d_in[5];
  const float* b2 = (const float*)d_in[6];
  const float* w3 = (const float*)d_in[7];
  const float* b3 = (const float*)d_in[8];
  const float* w4 = (const float*)d_in[9];
  const float* b4 = (const float*)d_in[10];
  const int* sparse = (const int*)d_in[11];

  float* ws = (float*)d_ws;
  float* xm = ws;                       // 25600 floats
  float* a_pad = ws + kAOffFloats;      // 3*16*64*25*28 = 2,150,400 floats
  float* y = (float*)d_out;

  k1_mean<<<kN * kC, 256, 0, stream>>>(x, xm);
  k2_attn<<<kS * kN, 256, 0, stream>>>(xm, Ag, alpha, w1, b1, w2, b2, w4, b4,
                                       sparse, a_pad);
  dim3 g3(kT / kTT, kN);
  k3_main<<<g3, 256, 0, stream>>>(x, w3, b3, a_pad, sparse, y);
}

// Round 2
// 127.130 us; speedup vs baseline: 2.0295x; 2.0295x over previous
//
#include <hip/hip_runtime.h>
#include <cmath>

typedef __bf16 bf16x8 __attribute__((ext_vector_type(8)));
typedef float f32x4 __attribute__((ext_vector_type(4)));

namespace {
constexpr int kN = 16, kC = 64, kT = 512, kV = 25, kS = 3, kR = 8, kO = 64;
constexpr int kTV = kT * kV;  // 12800
constexpr int kTT = 8;        // t rows per k3 block
// ws byte layout: xm f32 [16*64*25] | a_frag bf16 [48][8192][16B] | w3 frags
constexpr size_t WS_AFRAG = 102400;
constexpr size_t WS_W3F = WS_AFRAG + (size_t)48 * 131072;  // 6393856
}  // namespace

// XsT: bf16 [col=(t*32+u) 256][c' 64], swizzled, bytes 0..32768
__device__ __forceinline__ int swzA(int col, int cbyte) {
  return ((col << 7) + cbyte) ^ ((col & 7) << 4);
}
// X3s: bf16 [t 8][c 64][u 32], swizzled, bytes 32768..65536
__device__ __forceinline__ int swzB(int t, int c, int ubyte) {
  int lin = ((t & 7) << 12) + (c << 6) + ubyte;
  int sw = ((t & 7) ^ ((c >> 2) & 7)) << 4;
  return 32768 + (lin ^ sw);
}

// ---------------- k1: xm[n,c,v] = mean_t x[n,c,t,v] (coalesced f4 + LDS bounce)
__global__ __launch_bounds__(256) void k1_mean(const float* __restrict__ x,
                                               float* __restrict__ xm) {
  const int bid = blockIdx.x;  // n*64 + c
  __shared__ float tile[256 * 25];
  __shared__ float part[25][11];
  const int tid = threadIdx.x;
  const float4* xg4 = (const float4*)(x + (size_t)bid * kTV);
  const int v = tid / 10, k = tid % 10;  // valid when tid < 250
  float psum = 0.f;
  for (int half = 0; half < 2; ++half) {
    __syncthreads();
    for (int i4 = tid; i4 < 1600; i4 += 256)
      ((float4*)tile)[i4] = xg4[half * 1600 + i4];
    __syncthreads();
    if (tid < 250)
      for (int t = k; t < 256; t += 10) psum += tile[t * 25 + v];
  }
  if (tid < 250) part[v][k] = psum;
  __syncthreads();
  if (tid < 25) {
    float s = 0.f;
#pragma unroll
    for (int kk = 0; kk < 10; ++kk) s += part[tid][kk];
    xm[bid * 25 + tid] = s * (1.f / 512.f);
  }
}

// ---------------- k2: build a_frag (bf16, MFMA-B order, bias/colsum folded) + w3 frags
__global__ __launch_bounds__(256) void k2_attn(
    const float* __restrict__ xm, const float* __restrict__ Ag,
    const float* __restrict__ alpha, const float* __restrict__ w1,
    const float* __restrict__ b1, const float* __restrict__ w2,
    const float* __restrict__ b2, const float* __restrict__ w3,
    const float* __restrict__ w4, const float* __restrict__ b4,
    const int* __restrict__ sparse, unsigned char* __restrict__ ws) {
  const float thr = (float)sparse[0];
  const int s = blockIdx.x >> 4, n = blockIdx.x & 15;
  __shared__ float xm_l[1600];
  __shared__ float x1_l[200], x2_l[200];
  __shared__ float att_l[8 * 625];
  __shared__ float attsum_l[200];
  __shared__ float ag_l[625];
  __shared__ float acs_l[25];
  __shared__ float w4_l[512];
  const int tid = threadIdx.x;
  for (int i = tid; i < 1600; i += 256) xm_l[i] = xm[n * 1600 + i];
  for (int i = tid; i < 512; i += 256) {
    float w = w4[s * 512 + i];
    w4_l[i] = (fabsf(w) > thr) ? w : 0.f;
  }
  for (int i = tid; i < 625; i += 256) ag_l[i] = Ag[s * 625 + i];
  __syncthreads();
  // x1[r,u], x2[r,v]
  for (int i = tid; i < 400; i += 256) {
    int which = i / 200, idx = i % 200, r = idx / 25, u = idx % 25;
    const float* wrow = (which == 0 ? w1 : w2) + (s * 8 + r) * 64;
    float acc = 0.f;
    for (int cc = 0; cc < 64; ++cc) {
      float w = wrow[cc];
      w = (fabsf(w) > thr) ? w : 0.f;
      acc += w * xm_l[cc * 25 + u];
    }
    acc += (which == 0 ? b1 : b2)[s * 8 + r];
    if (which == 0) x1_l[idx] = acc;
    else x2_l[idx] = acc;
  }
  __syncthreads();
  for (int i = tid; i < 8 * 625; i += 256) {
    int r = i / 625, uv = i % 625, u = uv / 25, v = uv % 25;
    att_l[i] = tanhf(x1_l[r * 25 + u] - x2_l[r * 25 + v]);
  }
  __syncthreads();
  if (tid < 200) {
    int r = tid / 25, v = tid % 25;
    float sum = 0.f;
    for (int u = 0; u < 25; ++u) sum += att_l[r * 625 + u * 25 + v];
    attsum_l[tid] = sum;
  } else if (tid < 225) {
    int v = tid - 200;
    float sum = 0.f;
    for (int u = 0; u < 25; ++u) sum += ag_l[u * 25 + v];
    acs_l[v] = sum;
  }
  __syncthreads();
  const float al = alpha[0];
  // a_ext[c][u][v]: u<25 -> a ; u==25 -> colsum(a) (bias-fold partner) ; u>25 -> 0
  // frag order: slot = c*128 + vt*64 + lane ; elem j -> u = 8*(lane>>4)+j, v = vt*16+(lane&15)
  unsigned char* afrag = ws + WS_AFRAG + (size_t)(s * 16 + n) * 131072;
  for (int slot = tid; slot < 8192; slot += 256) {
    int c = slot >> 7, vt = (slot >> 6) & 1, l = slot & 63;
    int v = vt * 16 + (l & 15), g = l >> 4;
    bf16x8 out;
    if (v < 25) {
      float b4v = b4[s * 64 + c];
#pragma unroll
      for (int j = 0; j < 8; ++j) {
        int u = g * 8 + j;
        float val = 0.f;
        if (u < 25) {
          float acc = 0.f;
#pragma unroll
          for (int r = 0; r < 8; ++r) acc += w4_l[c * 8 + r] * att_l[r * 625 + u * 25 + v];
          val = al * (acc + b4v) + ag_l[u * 25 + v];
        } else if (u == 25) {
          float acc = 0.f;
#pragma unroll
          for (int r = 0; r < 8; ++r) acc += w4_l[c * 8 + r] * attsum_l[r * 25 + v];
          val = al * acc + 25.f * al * b4v + acs_l[v];
        }
        out[j] = (__bf16)val;
      }
    } else {
#pragma unroll
      for (int j = 0; j < 8; ++j) out[j] = (__bf16)0.f;
    }
    *(bf16x8*)(afrag + (size_t)slot * 16) = out;
  }
  // w3 A-frags: slot = ot*128 + ks*64 + lane ; elem j -> o=16ot+(l&15), cp=32ks+8(l>>4)+j
  if (n == 0) {
    unsigned char* w3f = ws + WS_W3F + (size_t)s * 8192;
    for (int slot = tid; slot < 512; slot += 256) {
      int ot = slot >> 7, ks = (slot >> 6) & 1, l = slot & 63;
      int o = ot * 16 + (l & 15), g = l >> 4;
      bf16x8 out;
#pragma unroll
      for (int j = 0; j < 8; ++j) {
        int cp = ks * 32 + g * 8 + j;
        float w = w3[(s * 64 + o) * 64 + cp];
        out[j] = (__bf16)((fabsf(w) > thr) ? w : 0.f);
      }
      *(bf16x8*)(w3f + slot * 16) = out;
    }
  }
}

// ---------------- k3: MFMA GEMM1 (W3·X) -> LDS transpose -> MFMA GEMM2 (X3·a) + residual relu
__global__ __launch_bounds__(512, 2) void k3_main(const float* __restrict__ x,
                                                  const float* __restrict__ b3,
                                                  const unsigned char* __restrict__ ws,
                                                  float* __restrict__ y) {
  const int tb = blockIdx.x;  // 0..63 (8-t chunks)
  const int n = blockIdx.y;   // 0..15
  __shared__ __align__(16) unsigned char smem[65536];
  const int tid = threadIdx.x;
  const int w = tid >> 6, l = tid & 63, g = l >> 4, l15 = l & 15;

  const float4* xg4 = (const float4*)(x + (size_t)n * kC * kTV);

  // zero u=25..31 pad columns of XsT (pairs of c as u32)
  for (int idx = tid; idx < 1792; idx += 512) {
    int t = idx / 224, rem = idx % 224;
    int u = 25 + rem / 32, cp2 = rem % 32;
    *(unsigned int*)(smem + swzA(t * 32 + u, cp2 * 4)) = 0u;
  }
  // stage x -> XsT bf16 (coalesced f4 global reads, scattered b16 LDS writes)
  for (int i4 = tid; i4 < 3200; i4 += 512) {
    int c = i4 / 50, r4 = i4 % 50;
    float4 vv = xg4[c * 3200 + tb * 50 + r4];
    float vals[4] = {vv.x, vv.y, vv.z, vv.w};
    int lin = r4 * 4;
#pragma unroll
    for (int kk = 0; kk < 4; ++kk) {
      int t = (lin + kk) / 25, u = (lin + kk) % 25;
      *(__bf16*)(smem + swzA(t * 32 + u, c * 2)) = (__bf16)vals[kk];
    }
  }
  __syncthreads();

  const unsigned char* afrag = ws + WS_AFRAG;
  const unsigned char* w3f = ws + WS_W3F;

  f32x4 zacc[8][2];
#pragma unroll
  for (int cc = 0; cc < 8; ++cc)
#pragma unroll
    for (int vt = 0; vt < 2; ++vt) {
      f32x4 zz = {0.f, 0.f, 0.f, 0.f};
      zacc[cc][vt] = zz;
    }

  for (int s = 0; s < kS; ++s) {
    // A1 frags: W3 masked bf16 (L2-hot)
    bf16x8 A1[4][2];
#pragma unroll
    for (int ot = 0; ot < 4; ++ot)
#pragma unroll
      for (int ks = 0; ks < 2; ++ks)
        A1[ot][ks] = *(const bf16x8*)(w3f + s * 8192 + ((ot * 2 + ks) * 64 + l) * 16);
    // B2 frags: a_ext for this wave's 8 channels (coalesced 16B, L2-hot)
    bf16x8 B2[8][2];
    const unsigned char* af = afrag + (size_t)(s * 16 + n) * 131072;
#pragma unroll
    for (int cc = 0; cc < 8; ++cc) {
      int c = w * 8 + cc;
#pragma unroll
      for (int vt = 0; vt < 2; ++vt)
        B2[cc][vt] = *(const bf16x8*)(af + ((c * 2 + vt) * 64 + l) * 16);
    }
    if (s) __syncthreads();  // prev GEMM2 reads done before X3s overwrite

    // GEMM1: wave w owns t-row w (cols 32w..32w+31)
    f32x4 acc[2][4];
#pragma unroll
    for (int cti = 0; cti < 2; ++cti) {
      bf16x8 b1k0 = *(const bf16x8*)(smem + swzA(w * 32 + cti * 16 + l15, g * 16));
      bf16x8 b1k1 = *(const bf16x8*)(smem + swzA(w * 32 + cti * 16 + l15, 64 + g * 16));
#pragma unroll
      for (int ot = 0; ot < 4; ++ot) {
        f32x4 d = {0.f, 0.f, 0.f, 0.f};
        d = __builtin_amdgcn_mfma_f32_16x16x32_bf16(A1[ot][0], b1k0, d, 0, 0, 0);
        d = __builtin_amdgcn_mfma_f32_16x16x32_bf16(A1[ot][1], b1k1, d, 0, 0, 0);
        acc[cti][ot] = d;
      }
    }
    // scatter X3 -> X3s[t=w][c][u] bf16 (u=25 reserved for bias row)
#pragma unroll
    for (int cti = 0; cti < 2; ++cti) {
      int u = cti * 16 + l15;
      if (u != 25) {
#pragma unroll
        for (int ot = 0; ot < 4; ++ot)
#pragma unroll
          for (int jj = 0; jj < 4; ++jj) {
            int o = ot * 16 + g * 4 + jj;
            *(__bf16*)(smem + swzB(w, o, u * 2)) = (__bf16)acc[cti][ot][jj];
          }
      }
    }
    // bias row: X3s[t][c][25] = b3[s][c]
    {
      int t = tid >> 6, c = tid & 63;
      *(__bf16*)(smem + swzB(t, c, 50)) = (__bf16)b3[s * 64 + c];
    }
    __syncthreads();
    // GEMM2: z[t,v] += X3s[c] · a_ext[c]   (8 channels per wave)
#pragma unroll
    for (int cc = 0; cc < 8; ++cc) {
      int c = w * 8 + cc;
      bf16x8 a2 = *(const bf16x8*)(smem + swzB(l15, c, g * 16));  // t = l15&7 (dups discarded)
      zacc[cc][0] = __builtin_amdgcn_mfma_f32_16x16x32_bf16(a2, B2[cc][0], zacc[cc][0], 0, 0, 0);
      zacc[cc][1] = __builtin_amdgcn_mfma_f32_16x16x32_bf16(a2, B2[cc][1], zacc[cc][1], 0, 0, 0);
    }
  }
  __syncthreads();  // all LDS reads done; reuse smem as z-stage (f32 [64][200])
  float* zs = (float*)smem;
  if (g < 2) {
#pragma unroll
    for (int cc = 0; cc < 8; ++cc) {
      int c = w * 8 + cc;
#pragma unroll
      for (int vt = 0; vt < 2; ++vt) {
        int v = vt * 16 + l15;
        if (v < 25) {
#pragma unroll
          for (int jj = 0; jj < 4; ++jj)
            zs[c * 200 + (g * 4 + jj) * 25 + v] = zacc[cc][vt][jj];
        }
      }
    }
  }
  __syncthreads();
  float4* yg4 = (float4*)(y + (size_t)n * kC * kTV);
  for (int i4 = tid; i4 < 3200; i4 += 512) {
    int c = i4 / 50, r4 = i4 % 50;
    float4 xv = xg4[c * 3200 + tb * 50 + r4];
    float4 zv = *(float4*)(zs + c * 200 + r4 * 4);
    float4 o;
    o.x = fmaxf(zv.x + xv.x, 0.f);
    o.y = fmaxf(zv.y + xv.y, 0.f);
    o.z = fmaxf(zv.z + xv.z, 0.f);
    o.w = fmaxf(zv.w + xv.w, 0.f);
    yg4[c * 3200 + tb * 50 + r4] = o;
  }
}

extern "C" void kernel_launch(void* const* d_in, const int* in_sizes, int n_in,
                              void* d_out, int out_size, void* d_ws, size_t ws_size,
                              hipStream_t stream) {
  const float* x = (const float*)d_in[0];
  const float* Ag = (const float*)d_in[1];
  const float* alpha = (const float*)d_in[2];
  const float* w1 = (const float*)d_in[3];
  const float* b1 = (const float*)d_in[4];
  const float* w2 = (const float*)d_in[5];
  const float* b2 = (const float*)d_in[6];
  const float* w3 = (const float*)d_in[7];
  const float* b3 = (const float*)d_in[8];
  const float* w4 = (const float*)d_in[9];
  const float* b4 = (const float*)d_in[10];
  const int* sparse = (const int*)d_in[11];

  unsigned char* ws = (unsigned char*)d_ws;
  float* xm = (float*)ws;  // [16][64][25] f32
  float* y = (float*)d_out;

  k1_mean<<<kN * kC, 256, 0, stream>>>(x, xm);
  k2_attn<<<kS * kN, 256, 0, stream>>>(xm, Ag, alpha, w1, b1, w2, b2, w3, w4, b4,
                                       sparse, ws);
  dim3 g3(kT / kTT, kN);
  k3_main<<<g3, 512, 0, stream>>>(x, b3, ws, y);
}

// Round 3
// 88.270 us; speedup vs baseline: 2.9230x; 1.4402x over previous
//
#include <hip/hip_runtime.h>
#include <cmath>

typedef __bf16 bf16x8 __attribute__((ext_vector_type(8)));
typedef float f32x4 __attribute__((ext_vector_type(4)));

namespace {
constexpr int kN = 16, kC = 64, kT = 512, kV = 25, kS = 3, kR = 8, kO = 64;
constexpr int kTV = kT * kV;  // 12800
constexpr int kTT = 16;       // t rows per k3 block
// ws byte layout: xm f32 [16*64*25] | a_frag bf16 [48][8192][16B] | w3 frags
constexpr size_t WS_AFRAG = 102400;
constexpr size_t WS_W3F = WS_AFRAG + (size_t)48 * 131072;  // 6393856
}  // namespace

// XsT: bf16 [col=(t*32+u) 512][c' 64] swizzled, bytes [0, 65536)
__device__ __forceinline__ int swzA(int col, int cbyte) {
  return ((col << 7) + cbyte) ^ ((col & 7) << 4);
}
// X3s: bf16 [c 64][t 16][u 32] swizzled, bytes [65536, 131072)
__device__ __forceinline__ int swzB(int c, int t, int ubyte) {
  return 65536 + (c << 10) + (((t << 6) + ubyte) ^ ((t & 7) << 4));
}

// ---------------- k1: xm[n,c,v] = mean_t x[n,c,t,v] (single-pass LDS bounce)
__global__ __launch_bounds__(512) void k1_mean(const float* __restrict__ x,
                                               float* __restrict__ xm) {
  const int bid = blockIdx.x;  // n*64 + c
  __shared__ float tile[kTV];       // 51.2 KB
  __shared__ float part[25][20];
  const int tid = threadIdx.x;
  const float4* xg4 = (const float4*)(x + (size_t)bid * kTV);
  for (int i4 = tid; i4 < 3200; i4 += 512) ((float4*)tile)[i4] = xg4[i4];
  __syncthreads();
  if (tid < 500) {
    const int v = tid / 20, k = tid % 20;
    float psum = 0.f;
    for (int t = k; t < kT; t += 20) psum += tile[t * 25 + v];
    part[v][k] = psum;
  }
  __syncthreads();
  if (tid < 25) {
    float s = 0.f;
#pragma unroll
    for (int kk = 0; kk < 20; ++kk) s += part[tid][kk];
    xm[bid * 25 + tid] = s * (1.f / 512.f);
  }
}

// ---------------- k2: a_frag (bf16, MFMA-B order, bias/colsum folded) + w3 frags
__global__ __launch_bounds__(256) void k2_attn(
    const float* __restrict__ xm, const float* __restrict__ Ag,
    const float* __restrict__ alpha, const float* __restrict__ w1,
    const float* __restrict__ b1, const float* __restrict__ w2,
    const float* __restrict__ b2, const float* __restrict__ w3,
    const float* __restrict__ w4, const float* __restrict__ b4,
    const int* __restrict__ sparse, unsigned char* __restrict__ ws) {
  const float thr = (float)sparse[0];
  const int b = blockIdx.x;
  const int s = b >> 6, n = (b >> 2) & 15, q = b & 3;  // q: c-quarter
  __shared__ float xm_l[1600];
  __shared__ float x1_l[200], x2_l[200];
  __shared__ float att_l[8 * 625];
  __shared__ float attsum_l[200];
  __shared__ float ag_l[625];
  __shared__ float acs_l[25];
  __shared__ float w4_l[512];
  const int tid = threadIdx.x;
  for (int i = tid; i < 1600; i += 256) xm_l[i] = xm[n * 1600 + i];
  for (int i = tid; i < 512; i += 256) {
    float w = w4[s * 512 + i];
    w4_l[i] = (fabsf(w) > thr) ? w : 0.f;
  }
  for (int i = tid; i < 625; i += 256) ag_l[i] = Ag[s * 625 + i];
  __syncthreads();
  for (int i = tid; i < 400; i += 256) {
    int which = i / 200, idx = i % 200, r = idx / 25, u = idx % 25;
    const float* wrow = (which == 0 ? w1 : w2) + (s * 8 + r) * 64;
    float acc = 0.f;
    for (int cc = 0; cc < 64; ++cc) {
      float w = wrow[cc];
      w = (fabsf(w) > thr) ? w : 0.f;
      acc += w * xm_l[cc * 25 + u];
    }
    acc += (which == 0 ? b1 : b2)[s * 8 + r];
    if (which == 0) x1_l[idx] = acc;
    else x2_l[idx] = acc;
  }
  __syncthreads();
  for (int i = tid; i < 8 * 625; i += 256) {
    int r = i / 625, uv = i % 625, u = uv / 25, v = uv % 25;
    att_l[i] = tanhf(x1_l[r * 25 + u] - x2_l[r * 25 + v]);
  }
  __syncthreads();
  if (tid < 200) {
    int r = tid / 25, v = tid % 25;
    float sum = 0.f;
    for (int u = 0; u < 25; ++u) sum += att_l[r * 625 + u * 25 + v];
    attsum_l[tid] = sum;
  } else if (tid < 225) {
    int v = tid - 200;
    float sum = 0.f;
    for (int u = 0; u < 25; ++u) sum += ag_l[u * 25 + v];
    acs_l[v] = sum;
  }
  __syncthreads();
  const float al = alpha[0];
  // a_ext[c][u][v]: u<25 -> a ; u==25 -> colsum(a) ; u>25 -> 0
  // slot = c*128 + vt*64 + lane ; elem j -> u = 8*(lane>>4)+j, v = vt*16+(lane&15)
  unsigned char* afrag = ws + WS_AFRAG + (size_t)(s * 16 + n) * 131072;
  for (int slot = q * 2048 + tid; slot < (q + 1) * 2048; slot += 256) {
    int c = slot >> 7, vt = (slot >> 6) & 1, l = slot & 63;
    int v = vt * 16 + (l & 15), g = l >> 4;
    bf16x8 out;
    if (v < 25) {
      float b4v = b4[s * 64 + c];
#pragma unroll
      for (int j = 0; j < 8; ++j) {
        int u = g * 8 + j;
        float val = 0.f;
        if (u < 25) {
          float acc = 0.f;
#pragma unroll
          for (int r = 0; r < 8; ++r) acc += w4_l[c * 8 + r] * att_l[r * 625 + u * 25 + v];
          val = al * (acc + b4v) + ag_l[u * 25 + v];
        } else if (u == 25) {
          float acc = 0.f;
#pragma unroll
          for (int r = 0; r < 8; ++r) acc += w4_l[c * 8 + r] * attsum_l[r * 25 + v];
          val = al * acc + 25.f * al * b4v + acs_l[v];
        }
        out[j] = (__bf16)val;
      }
    } else {
#pragma unroll
      for (int j = 0; j < 8; ++j) out[j] = (__bf16)0.f;
    }
    *(bf16x8*)(afrag + (size_t)slot * 16) = out;
  }
  // w3 A-frags: slot = ot*128 + ks*64 + lane ; elem j -> o=16ot+(l&15), cp=32ks+8(l>>4)+j
  if (n == 0 && tid < 128) {
    unsigned char* w3f = ws + WS_W3F + (size_t)s * 8192;
    int slot = q * 128 + tid;
    int ot = slot >> 7, ks = (slot >> 6) & 1, l = slot & 63;
    int o = ot * 16 + (l & 15), g = l >> 4;
    bf16x8 out;
#pragma unroll
    for (int j = 0; j < 8; ++j) {
      int cp = ks * 32 + g * 8 + j;
      float w = w3[(s * 64 + o) * 64 + cp];
      out[j] = (__bf16)((fabsf(w) > thr) ? w : 0.f);
    }
    *(bf16x8*)(w3f + slot * 16) = out;
  }
}

// ---------------- k3: GEMM1 (W3·X) -> LDS -> GEMM2 (X3·a_ext) -> residual relu
__global__ __launch_bounds__(512, 2) void k3_main(const float* __restrict__ x,
                                                  const float* __restrict__ b3,
                                                  const unsigned char* __restrict__ ws,
                                                  float* __restrict__ y) {
  const int n = blockIdx.x;   // 0..15  (linear_id%8 == n%8 -> same-n blocks share XCD)
  const int tb = blockIdx.y;  // 0..31 (16-t chunks)
  extern __shared__ __align__(16) unsigned char smem[];  // 131072 dynamic
  const int tid = threadIdx.x;
  const int w = tid >> 6, l = tid & 63, g = l >> 4, l15 = l & 15;

  const float4* xg4 = (const float4*)(x + (size_t)n * kC * kTV);

  // zero X3s u=26..31 pad (once; scatter never touches them; NaN*0 hazard)
  for (int idx = tid; idx < 3072; idx += 512) {
    int c = idx / 48, r = idx % 48, t = r / 3, ub = 52 + (r % 3) * 4;
    *(unsigned int*)(smem + swzB(c, t, ub)) = 0u;
  }
  // stage x[n,:,16t,25v] -> XsT bf16 (coalesced f4 reads, scattered b16 writes)
  for (int i4 = tid; i4 < 6400; i4 += 512) {
    int c = i4 / 100, r4 = i4 % 100;
    float4 vv = xg4[c * 3200 + tb * 100 + r4];
    float vals[4] = {vv.x, vv.y, vv.z, vv.w};
    int lin = r4 * 4;
#pragma unroll
    for (int kk = 0; kk < 4; ++kk) {
      int t = (lin + kk) / 25, u = (lin + kk) % 25;
      *(__bf16*)(smem + swzA(t * 32 + u, c * 2)) = (__bf16)vals[kk];
    }
  }
  __syncthreads();

  const unsigned char* afrag = ws + WS_AFRAG;
  const unsigned char* w3f = ws + WS_W3F;

  f32x4 zacc[8][2];
#pragma unroll
  for (int cc = 0; cc < 8; ++cc)
#pragma unroll
    for (int vt = 0; vt < 2; ++vt) {
      f32x4 zz = {0.f, 0.f, 0.f, 0.f};
      zacc[cc][vt] = zz;
    }

  for (int s = 0; s < kS; ++s) {
    // A1 frags: masked W3 (global, L2-hot)
    bf16x8 A1[4][2];
#pragma unroll
    for (int ot = 0; ot < 4; ++ot)
#pragma unroll
      for (int ks = 0; ks < 2; ++ks)
        A1[ot][ks] = *(const bf16x8*)(w3f + s * 8192 + ((ot * 2 + ks) * 64 + l) * 16);
    if (s) __syncthreads();  // GEMM2(s-1) X3s reads done before overwrite

    // GEMM1: wave w owns cols [64w, 64w+64) of (t*32+u); 4 ctiles x 4 otiles
    f32x4 acc[4][4];
#pragma unroll
    for (int cti = 0; cti < 4; ++cti) {
      int col = w * 64 + cti * 16 + l15;
      bf16x8 bk0 = *(const bf16x8*)(smem + swzA(col, g * 16));
      bf16x8 bk1 = *(const bf16x8*)(smem + swzA(col, 64 + g * 16));
#pragma unroll
      for (int ot = 0; ot < 4; ++ot) {
        f32x4 d = {0.f, 0.f, 0.f, 0.f};
        d = __builtin_amdgcn_mfma_f32_16x16x32_bf16(A1[ot][0], bk0, d, 0, 0, 0);
        d = __builtin_amdgcn_mfma_f32_16x16x32_bf16(A1[ot][1], bk1, d, 0, 0, 0);
        acc[cti][ot] = d;
      }
    }
    // scatter X3 -> X3s[c][t][u] (u<25)
#pragma unroll
    for (int cti = 0; cti < 4; ++cti) {
      int col = w * 64 + cti * 16 + l15;
      int t = col >> 5, u = col & 31;
      if (u < 25) {
#pragma unroll
        for (int ot = 0; ot < 4; ++ot)
#pragma unroll
          for (int jj = 0; jj < 4; ++jj) {
            int o = ot * 16 + g * 4 + jj;
            *(__bf16*)(smem + swzB(o, t, u * 2)) = (__bf16)acc[cti][ot][jj];
          }
      }
    }
    // bias row u=25: X3s[c][t][25] = b3[s][c]
    for (int slot = tid; slot < 1024; slot += 512) {
      int c = slot >> 4, t = slot & 15;
      *(__bf16*)(smem + swzB(c, t, 50)) = (__bf16)b3[s * 64 + c];
    }
    // B2 frags for GEMM2 (issue before barrier; GEMM1 accs already dead)
    bf16x8 B2[8][2];
    const unsigned char* af = afrag + (size_t)(s * 16 + n) * 131072;
#pragma unroll
    for (int cc = 0; cc < 8; ++cc) {
      int c = w * 8 + cc;
#pragma unroll
      for (int vt = 0; vt < 2; ++vt)
        B2[cc][vt] = *(const bf16x8*)(af + ((c * 2 + vt) * 64 + l) * 16);
    }
    __syncthreads();
    // GEMM2: z[t,v] += X3s[c] . a_ext[c]  (8 channels per wave, full M=16t)
#pragma unroll
    for (int cc = 0; cc < 8; ++cc) {
      int c = w * 8 + cc;
      bf16x8 a2 = *(const bf16x8*)(smem + swzB(c, l15, g * 16));
      zacc[cc][0] = __builtin_amdgcn_mfma_f32_16x16x32_bf16(a2, B2[cc][0], zacc[cc][0], 0, 0, 0);
      zacc[cc][1] = __builtin_amdgcn_mfma_f32_16x16x32_bf16(a2, B2[cc][1], zacc[cc][1], 0, 0, 0);
    }
  }
  __syncthreads();  // all LDS reads done; reuse smem as zs f32 [64][400]
  float* zs = (float*)smem;
#pragma unroll
  for (int cc = 0; cc < 8; ++cc) {
    int c = w * 8 + cc;
#pragma unroll
    for (int vt = 0; vt < 2; ++vt) {
      int v = vt * 16 + l15;
      if (v < 25) {
#pragma unroll
        for (int jj = 0; jj < 4; ++jj) {
          int t = g * 4 + jj;
          zs[c * 400 + t * 25 + v] = zacc[cc][vt][jj];
        }
      }
    }
  }
  __syncthreads();
  float4* yg4 = (float4*)(y + (size_t)n * kC * kTV);
  for (int i4 = tid; i4 < 6400; i4 += 512) {
    int c = i4 / 100, r4 = i4 % 100;
    float4 xv = xg4[c * 3200 + tb * 100 + r4];
    float4 zv = *(const float4*)(zs + c * 400 + r4 * 4);
    float4 o;
    o.x = fmaxf(zv.x + xv.x, 0.f);
    o.y = fmaxf(zv.y + xv.y, 0.f);
    o.z = fmaxf(zv.z + xv.z, 0.f);
    o.w = fmaxf(zv.w + xv.w, 0.f);
    yg4[c * 3200 + tb * 100 + r4] = o;
  }
}

extern "C" void kernel_launch(void* const* d_in, const int* in_sizes, int n_in,
                              void* d_out, int out_size, void* d_ws, size_t ws_size,
                              hipStream_t stream) {
  const float* x = (const float*)d_in[0];
  const float* Ag = (const float*)d_in[1];
  const float* alpha = (const float*)d_in[2];
  const float* w1 = (const float*)d_in[3];
  const float* b1 = (const float*)d_in[4];
  const float* w2 = (const float*)d_in[5];
  const float* b2 = (const float*)d_in[6];
  const float* w3 = (const float*)d_in[7];
  const float* b3 = (const float*)d_in[8];
  const float* w4 = (const float*)d_in[9];
  const float* b4 = (const float*)d_in[10];
  const int* sparse = (const int*)d_in[11];

  unsigned char* ws = (unsigned char*)d_ws;
  float* xm = (float*)ws;  // [16][64][25] f32
  float* y = (float*)d_out;

  static bool attr_set = false;
  if (!attr_set) {
    hipFuncSetAttribute((const void*)k3_main,
                        hipFuncAttributeMaxDynamicSharedMemorySize, 131072);
    attr_set = true;
  }

  k1_mean<<<kN * kC, 512, 0, stream>>>(x, xm);
  k2_attn<<<kS * kN * 4, 256, 0, stream>>>(xm, Ag, alpha, w1, b1, w2, b2, w3, w4,
                                           b4, sparse, ws);
  dim3 g3(kN, kT / kTT);  // x=n (XCD affinity), y=tb
  k3_main<<<g3, 512, 131072, stream>>>(x, b3, ws, y);
}